// Round 1
// 1460.895 us; speedup vs baseline: 1.2716x; 1.2716x over previous
//
#include <hip/hip_runtime.h>
#include <cstdint>

// ---------------------------------------------------------------------------
// WindowAttention on MI355X, bf16 MFMA pipeline.
// This round: QKV & proj GEMMs rewritten to the 256^2 8-wave 8-phase
// schedule (T2-layout/T3/T4/T5): BK=64, 128KiB LDS double buffer,
// counted vmcnt(6), setprio around MFMA clusters, XCD-swizzled grid.
// Workspace layout (needs ~546 MB):
//   xw   : bf16 [65536][1024]  windowed x (reused as attention-out later)
//   qkvb : bf16 [3][256][16][256][64]   q/k/v per (s, win, head, t, d)
//   wq   : bf16 [3072][1024]
//   wp   : bf16 [1024][1024]
// ---------------------------------------------------------------------------

typedef __bf16 bfx8 __attribute__((ext_vector_type(8)));
typedef float  fx4  __attribute__((ext_vector_type(4)));

__device__ __forceinline__ unsigned short f2bf(float f) {
  union { float f; unsigned u; } v; v.f = f;
  return (unsigned short)((v.u + 0x7FFFu + ((v.u >> 16) & 1u)) >> 16);
}

__device__ __forceinline__ void load_lds16(const void* g, void* l) {
  __builtin_amdgcn_global_load_lds((const __attribute__((address_space(1))) void*)g,
                                   (__attribute__((address_space(3))) void*)l,
                                   16, 0, 0);
}

// --------------------------- f32 -> bf16 cast ------------------------------
__global__ void cvt_bf16(const float* __restrict__ in, unsigned short* __restrict__ out, int n) {
  int i = (blockIdx.x * 256 + threadIdx.x) * 8;
  if (i >= n) return;
  float4 v0 = ((const float4*)(in + i))[0];
  float4 v1 = ((const float4*)(in + i))[1];
  union { unsigned short s[8]; uint4 q; } o;
  o.s[0] = f2bf(v0.x); o.s[1] = f2bf(v0.y); o.s[2] = f2bf(v0.z); o.s[3] = f2bf(v0.w);
  o.s[4] = f2bf(v1.x); o.s[5] = f2bf(v1.y); o.s[6] = f2bf(v1.z); o.s[7] = f2bf(v1.w);
  *(uint4*)(out + i) = o.q;
}

// ------------------- pack x into windowed order, bf16 ----------------------
// m = ((b*8 + wh)*8 + ww)*256 + r*16 + c  ->  x[b][ (wh*16+r)*128 + ww*16+c ][:]
__global__ void pack_x_win(const float* __restrict__ x, unsigned short* __restrict__ xw) {
  int64_t idx = (int64_t)blockIdx.x * 256 + threadIdx.x;   // 8M threads
  int m = (int)(idx >> 7);
  int c = ((int)idx & 127) << 3;
  int win = m >> 8, t = m & 255;
  int b = win >> 6, wh = (win >> 3) & 7, ww = win & 7;
  int n = ((wh << 4) + (t >> 4)) * 128 + (ww << 4) + (t & 15);
  const float* src = x + (((int64_t)b * 16384 + n) << 10) + c;
  float4 v0 = ((const float4*)src)[0];
  float4 v1 = ((const float4*)src)[1];
  union { unsigned short s[8]; uint4 q; } o;
  o.s[0] = f2bf(v0.x); o.s[1] = f2bf(v0.y); o.s[2] = f2bf(v0.z); o.s[3] = f2bf(v0.w);
  o.s[4] = f2bf(v1.x); o.s[5] = f2bf(v1.y); o.s[6] = f2bf(v1.z); o.s[7] = f2bf(v1.w);
  *(uint4*)(xw + ((int64_t)m << 10) + c) = o.q;
}

// ------------------- 256x256-tile 8-phase bf16 GEMM (B^T) ------------------
// C[m][n] = sum_k A[m][k] * B[n][k], K = 1024, BK = 64, 512 threads (8 waves
// as 2Mx4N), each wave owns a 128x64 output. LDS: 2 dbuf x {A,B} x {k-half}
// regions of 256 rows x 32 shorts = 8 x 16KB = 128KB.
// Region short-offset: base(b,op,kh) = b*32768 + op*16384 + kh*8192.
// K-tile kt lives in buf[kt&1]. Per iteration (2 K-tiles, 8 phases):
//   phase = (buf, miH, ks); 16 MFMA each; one half-tile staged per phase;
//   vmcnt(6) at phases 3 and 7 only (3 stagings in flight).
// Staging schedule (iter i): p0: A(2i+1,k1); p1..p4: B(2i+2,k0),A(2i+2,k0),
//   B(2i+2,k1),A(2i+2,k1); p5..p7: B(2i+3,k0),A(2i+3,k0),B(2i+3,k1).
// Hand-checked RAW (stagings complete >=1 vmcnt before first read) and WAR
// (each region's last ds_read is >=1 phase before its overwrite).
// EPI 0: qkv epilogue (RoPE on q,k; write bf16 [s][win][h][t][d])
// EPI 1: proj epilogue (un-window; write fp32 to d_out)
// ---------------------------------------------------------------------------

#define STAGE(SRC, DB) do {                                                   \
    load_lds16((SRC) + soff0, &lds[(DB) + doff0]);                            \
    load_lds16((SRC) + soff1, &lds[(DB) + doff1]);                            \
  } while (0)

// VM: 0 = no wait, 1 = vmcnt(6) (steady), 2 = vmcnt(0) (final-iter drain)
#define PHASE(BB, MIH, KS, LOADB, STG, VM) do {                               \
    if (LOADB) {                                                              \
      const unsigned short* bp_ = &lds[(BB)*32768 + 16384 + (KS)*8192 + boff];\
      bK[0] = *(const bfx8*)(bp_);                                            \
      bK[1] = *(const bfx8*)(bp_ + 512);                                      \
      bK[2] = *(const bfx8*)(bp_ + 1024);                                     \
      bK[3] = *(const bfx8*)(bp_ + 1536);                                     \
    }                                                                         \
    { const unsigned short* ap_ = &lds[(BB)*32768 + (KS)*8192 + (MIH)*2048 + aoff]; \
      af[0] = *(const bfx8*)(ap_);                                            \
      af[1] = *(const bfx8*)(ap_ + 512);                                      \
      af[2] = *(const bfx8*)(ap_ + 1024);                                     \
      af[3] = *(const bfx8*)(ap_ + 1536); }                                   \
    STG;                                                                      \
    if ((VM) == 1) asm volatile("s_waitcnt vmcnt(6)" ::: "memory");           \
    if ((VM) == 2) asm volatile("s_waitcnt vmcnt(0)" ::: "memory");           \
    __builtin_amdgcn_s_barrier();                                             \
    asm volatile("s_waitcnt lgkmcnt(0)" ::: "memory");                        \
    __builtin_amdgcn_sched_barrier(0);                                        \
    __builtin_amdgcn_s_setprio(1);                                            \
    _Pragma("unroll")                                                         \
    for (int mi_ = 0; mi_ < 4; mi_++)                                         \
      _Pragma("unroll")                                                       \
      for (int ni_ = 0; ni_ < 4; ni_++)                                       \
        acc[(MIH)*4 + mi_][ni_] = __builtin_amdgcn_mfma_f32_16x16x32_bf16(    \
            af[mi_], bK[ni_], acc[(MIH)*4 + mi_][ni_], 0, 0, 0);              \
    __builtin_amdgcn_s_setprio(0);                                            \
    __builtin_amdgcn_s_barrier();                                             \
  } while (0)

#define ITER(I, ST) do {                                                      \
    const int k2 = ((I) + 1) * 128;                                           \
    PHASE(0, 0, 0, 1, STAGE(srcA + k2 - 32, 40960), 0);                       \
    PHASE(0, 1, 0, 0, if (ST) STAGE(srcB + k2,      16384), 0);               \
    PHASE(0, 0, 1, 1, if (ST) STAGE(srcA + k2,      0),     0);               \
    PHASE(0, 1, 1, 0, if (ST) STAGE(srcB + k2 + 32, 24576), (ST) ? 1 : 2);    \
    PHASE(1, 0, 0, 1, if (ST) STAGE(srcA + k2 + 32, 8192),  0);               \
    PHASE(1, 1, 0, 0, if (ST) STAGE(srcB + k2 + 64, 49152), 0);               \
    PHASE(1, 0, 1, 1, if (ST) STAGE(srcA + k2 + 64, 32768), 0);               \
    PHASE(1, 1, 1, 0, if (ST) STAGE(srcB + k2 + 96, 57344), (ST) ? 1 : 2);    \
  } while (0)

template<int EPI, int NX>
__global__ __launch_bounds__(512, 2) void gemm8p(
    const unsigned short* __restrict__ A,
    const unsigned short* __restrict__ Bw,
    unsigned short* __restrict__ qkvb,
    float* __restrict__ outp)
{
  __shared__ unsigned short lds[65536];            // 128 KiB
  const int tid  = threadIdx.x;
  const int wave = tid >> 6, lane = tid & 63;
  const int lr = lane & 15, lg = lane >> 4;
  const int wave_m = wave >> 2, wave_n = wave & 3;

  // bijective XCD swizzle (nwg % 8 == 0): consecutive blocks on one XCD
  // share the A-panel (row tile), sweeping bx fastest.
  constexpr int GRID8 = NX * 256 / 8;
  const int bid = blockIdx.x;
  const int wg = (bid & 7) * GRID8 + (bid >> 3);
  const int bx = wg % NX, by = wg / NX;
  const int tileN = bx * 256, tileM = by * 256;

  const unsigned short* srcA = A  + (int64_t)tileM * 1024;
  const unsigned short* srcB = Bw + (int64_t)tileN * 1024;

  // staging: region = 256 rows x 32 shorts; chunk c = j*512 + wave*64 + lane
  // covers row c>>2, cols (c&3)*8..+7. LDS dest is wave-uniform + lane*16.
  const int c0 = wave * 64 + lane;
  const int c1 = 512 + c0;
  const int soff0 = (c0 >> 2) * 1024 + (c0 & 3) * 8;
  const int soff1 = (c1 >> 2) * 1024 + (c1 & 3) * 8;
  const int doff0 = (wave * 64) * 8;
  const int doff1 = (512 + wave * 64) * 8;

  // fragment read offsets (shorts): row stride 32, k-slice lg*8.
  // bank start = (row&1)<<4 | lg<<2 -> 8 lanes per 4-bank group = b128 floor,
  // conflict-free with linear layout (64B rows): no swizzle needed.
  const int aoff = (wave_m * 128 + lr) * 32 + lg * 8;
  const int boff = (wave_n * 64  + lr) * 32 + lg * 8;

  fx4 acc[8][4];
#pragma unroll
  for (int i = 0; i < 8; i++)
#pragma unroll
    for (int j = 0; j < 4; j++) acc[i][j] = {0.f, 0.f, 0.f, 0.f};
  bfx8 af[4], bK[4];

  // prologue: kt0 all 4 halves + kt1 {A k0, B k0, B k1}; kt1 A k1 comes at
  // iter0 p0 (uniform with steady state).
  STAGE(srcA,      0);
  STAGE(srcB,      16384);
  STAGE(srcA + 32, 8192);
  STAGE(srcB + 32, 24576);
  STAGE(srcA + 64, 32768);
  STAGE(srcB + 64, 49152);
  STAGE(srcB + 96, 57344);
  asm volatile("s_waitcnt vmcnt(0)" ::: "memory");
  __builtin_amdgcn_s_barrier();

#pragma unroll 1
  for (int i = 0; i < 7; ++i) { ITER(i, 1); }
  ITER(7, 0);

  if (EPI == 0) {
    // C/D: col f = tileN + wave_n*64 + ni*16 + lr, row m = tileM + wave_m*128
    //      + mi*16 + lg*4 + r. s and h uniform per wave.
    const int s = tileN >> 10;
    const int hbase = ((tileN >> 6) + wave_n) & 15;
    const bool rope = (s < 2);
    float invf[4];
#pragma unroll
    for (int ni = 0; ni < 4; ni++) {
      const int p = (ni * 16 + lr) >> 1;
      invf[ni] = __powf(10000.0f, -(float)p * (1.0f / 32.0f));
    }
    // pos = t>>4 for p<16 (fragment-constant), t&15 for p>=16: 24 sincos total
    float chh[8][2], shh[8][2], cww[4][2], sww[4][2];
#pragma unroll
    for (int mi = 0; mi < 8; mi++) {
      const float th = (float)(wave_m * 8 + mi);
      __sincosf(th * invf[0], &shh[mi][0], &chh[mi][0]);
      __sincosf(th * invf[1], &shh[mi][1], &chh[mi][1]);
    }
#pragma unroll
    for (int r = 0; r < 4; r++) {
      const float tw = (float)(lg * 4 + r);
      __sincosf(tw * invf[2], &sww[r][0], &cww[r][0]);
      __sincosf(tw * invf[3], &sww[r][1], &cww[r][1]);
    }
#pragma unroll
    for (int mi = 0; mi < 8; mi++) {
      const int m0 = tileM + wave_m * 128 + mi * 16 + lg * 4;
#pragma unroll
      for (int r = 0; r < 4; r++) {
        const int m = m0 + r;
        const int win = m >> 8, t = m & 255;
        unsigned short* dst = qkvb + ((((int64_t)s * 256 + win) * 16 + hbase) * 256 + t) * 64;
#pragma unroll
        for (int ni = 0; ni < 4; ni++) {
          float v = acc[mi][ni][r];
          float o = v;
          if (rope) {
            const float pv = __shfl_xor(v, 1);       // pair partner (d^1)
            const float cn = (ni < 2) ? chh[mi][ni] : cww[r][ni - 2];
            const float sn = (ni < 2) ? shh[mi][ni] : sww[r][ni - 2];
            o = (lr & 1) ? (v * cn + pv * sn) : (v * cn - pv * sn);
          }
          dst[ni * 16 + lr] = f2bf(o);
        }
      }
    }
  } else {
#pragma unroll
    for (int mi = 0; mi < 8; mi++) {
      const int m0 = tileM + wave_m * 128 + mi * 16 + lg * 4;
#pragma unroll
      for (int r = 0; r < 4; r++) {
        const int m = m0 + r;
        const int win = m >> 8, t = m & 255;
        const int b = win >> 6, wh = (win >> 3) & 7, ww = win & 7;
        const int n = ((wh << 4) + (t >> 4)) * 128 + (ww << 4) + (t & 15);
        float* dst = outp + (((int64_t)b * 16384 + n) << 10) + tileN + wave_n * 64;
#pragma unroll
        for (int ni = 0; ni < 4; ni++) dst[ni * 16 + lr] = acc[mi][ni][r];
      }
    }
  }
}

// ----------------------- windowed flash attention --------------------------
// 1 block per (win, head); 4 waves, wave w owns q rows [64w, 64w+64).
__global__ __launch_bounds__(256) void win_attn(
    const unsigned short* __restrict__ qkvb,
    unsigned short* __restrict__ aout)
{
  __shared__ unsigned short VT[64 * 264];       // V^T, padded stride 264
  __shared__ unsigned short Pl[4][64 * 32];     // per-wave P staging
  const int bx = blockIdx.x;
  const int win = bx >> 4, h = bx & 15;
  const int tid = threadIdx.x, wave = tid >> 6, lane = tid & 63;
  const int lr = lane & 15, lg = lane >> 4;

  const unsigned short* qp = qkvb + (((int64_t)(      win) * 16 + h) << 14);
  const unsigned short* kp = qkvb + (((int64_t)(256 + win) * 16 + h) << 14);
  const unsigned short* vp = qkvb + (((int64_t)(512 + win) * 16 + h) << 14);

  // stage V^T into LDS
  for (int i = tid; i < 2048; i += 256) {
    int t = i >> 3, dg = (i & 7) * 8;
    union { uint4 q; unsigned short s[8]; } v;
    v.q = *(const uint4*)(vp + t * 64 + dg);
#pragma unroll
    for (int j = 0; j < 8; j++) VT[(dg + j) * 264 + t] = v.s[j];
  }

  // Q fragments, resident across the whole K sweep
  bfx8 qf[4][2];
#pragma unroll
  for (int mi = 0; mi < 4; mi++)
#pragma unroll
    for (int ks = 0; ks < 2; ks++)
      qf[mi][ks] = *(const bfx8*)(qp + (wave * 64 + mi * 16 + lr) * 64 + ks * 32 + lg * 8);

  fx4 o[4][4];
#pragma unroll
  for (int i = 0; i < 4; i++)
#pragma unroll
    for (int j = 0; j < 4; j++) o[i][j] = {0.f, 0.f, 0.f, 0.f};
  float mrow[4][4], lrow[4][4];
#pragma unroll
  for (int i = 0; i < 4; i++)
#pragma unroll
    for (int r = 0; r < 4; r++) { mrow[i][r] = -INFINITY; lrow[i][r] = 0.f; }

  __syncthreads();

  for (int kc = 0; kc < 8; kc++) {              // 32 k-tokens per chunk
    bfx8 kf[2][2];
#pragma unroll
    for (int nt = 0; nt < 2; nt++)
#pragma unroll
      for (int ks = 0; ks < 2; ks++)
        kf[nt][ks] = *(const bfx8*)(kp + (kc * 32 + nt * 16 + lr) * 64 + ks * 32 + lg * 8);

    fx4 sa[4][2];
#pragma unroll
    for (int mi = 0; mi < 4; mi++)
#pragma unroll
      for (int nt = 0; nt < 2; nt++) sa[mi][nt] = {0.f, 0.f, 0.f, 0.f};
#pragma unroll
    for (int mi = 0; mi < 4; mi++)
#pragma unroll
      for (int nt = 0; nt < 2; nt++) {
        sa[mi][nt] = __builtin_amdgcn_mfma_f32_16x16x32_bf16(qf[mi][0], kf[nt][0], sa[mi][nt], 0, 0, 0);
        sa[mi][nt] = __builtin_amdgcn_mfma_f32_16x16x32_bf16(qf[mi][1], kf[nt][1], sa[mi][nt], 0, 0, 0);
      }

    // online softmax, rows = lg*4 + r per 16-lane group
#pragma unroll
    for (int mi = 0; mi < 4; mi++) {
#pragma unroll
      for (int r = 0; r < 4; r++) {
        float s0 = sa[mi][0][r] * 0.125f, s1 = sa[mi][1][r] * 0.125f;
        float mx = fmaxf(s0, s1);
        mx = fmaxf(mx, __shfl_xor(mx, 1));
        mx = fmaxf(mx, __shfl_xor(mx, 2));
        mx = fmaxf(mx, __shfl_xor(mx, 4));
        mx = fmaxf(mx, __shfl_xor(mx, 8));
        float mold = mrow[mi][r];
        float mnew = fmaxf(mold, mx);
        float alpha = __expf(mold - mnew);
        float p0 = __expf(s0 - mnew), p1 = __expf(s1 - mnew);
        float ps = p0 + p1;
        ps += __shfl_xor(ps, 1);
        ps += __shfl_xor(ps, 2);
        ps += __shfl_xor(ps, 4);
        ps += __shfl_xor(ps, 8);
        lrow[mi][r] = lrow[mi][r] * alpha + ps;
        mrow[mi][r] = mnew;
#pragma unroll
        for (int ni = 0; ni < 4; ni++) o[mi][ni][r] *= alpha;
        const int prow = mi * 16 + lg * 4 + r;
        Pl[wave][prow * 32 +      lr] = f2bf(p0);
        Pl[wave][prow * 32 + 16 + lr] = f2bf(p1);
      }
    }

    // P @ V chunk
    bfx8 pa[4], vb[4];
#pragma unroll
    for (int mi = 0; mi < 4; mi++) pa[mi] = *(const bfx8*)&Pl[wave][(mi * 16 + lr) * 32 + lg * 8];
#pragma unroll
    for (int ni = 0; ni < 4; ni++) vb[ni] = *(const bfx8*)&VT[(ni * 16 + lr) * 264 + kc * 32 + lg * 8];
#pragma unroll
    for (int mi = 0; mi < 4; mi++)
#pragma unroll
      for (int ni = 0; ni < 4; ni++)
        o[mi][ni] = __builtin_amdgcn_mfma_f32_16x16x32_bf16(pa[mi], vb[ni], o[mi][ni], 0, 0, 0);
  }

  // normalize + store bf16 [win*256+t][h*64+d]
#pragma unroll
  for (int mi = 0; mi < 4; mi++)
#pragma unroll
    for (int r = 0; r < 4; r++) {
      const int t = wave * 64 + mi * 16 + lg * 4 + r;
      const float inv = 1.0f / lrow[mi][r];
      unsigned short* dst = aout + ((int64_t)(win * 256 + t) << 10) + h * 64;
#pragma unroll
      for (int ni = 0; ni < 4; ni++) dst[ni * 16 + lr] = f2bf(o[mi][ni][r] * inv);
    }
}

// ---------------------------------------------------------------------------
extern "C" void kernel_launch(void* const* d_in, const int* in_sizes, int n_in,
                              void* d_out, int out_size, void* d_ws, size_t ws_size,
                              hipStream_t stream) {
  const float* x     = (const float*)d_in[0];
  // d_in[1] = position_ids (unused by the reference math; RoPE is window-local)
  const float* Wqkv  = (const float*)d_in[2];
  const float* Wproj = (const float*)d_in[3];
  float* out = (float*)d_out;

  uint8_t* ws = (uint8_t*)d_ws;
  unsigned short* xw   = (unsigned short*)(ws);                     // 134217728 B
  unsigned short* qkvb = (unsigned short*)(ws + 134217728ll);       // 402653184 B
  unsigned short* wq   = (unsigned short*)(ws + 536870912ll);       //   6291456 B
  unsigned short* wp   = (unsigned short*)(ws + 543162368ll);       //   2097152 B

  cvt_bf16<<<1536, 256, 0, stream>>>(Wqkv, wq, 3072 * 1024);
  cvt_bf16<<<512, 256, 0, stream>>>(Wproj, wp, 1024 * 1024);
  pack_x_win<<<32768, 256, 0, stream>>>(x, xw);

  gemm8p<0, 12><<<3072, 512, 0, stream>>>(xw, wq, qkvb, nullptr);
  win_attn<<<4096, 256, 0, stream>>>(qkvb, xw);   // xw reused as attn-out
  gemm8p<1, 4><<<1024, 512, 0, stream>>>(xw, wp, nullptr, out);
}